// Round 8
// baseline (445.641 us; speedup 1.0000x reference)
//
#include <hip/hip_runtime.h>

// CFConv, round 12. Insight: ~200us of total is FIXED harness overhead
// (round-2: single dispatch 1252us vs 1430 total) -> only GPU busy time
// matters. Edge body restored to the verified 110us round-1 form (TILE_M=64,
// 34816B pool, 4 barriers, grid 1024, (256,4), separate eperm/dsts/cols);
// ONE change: T14 issue-early on the rbf gather (the HBM-latency component) -
// next tile's 4 float4 loads issued after barrier (c), consumed after next
// barrier (a); HBM latency hides under GEMM2+atomics. +16 named VGPRs only.
// Aux chain = round-10 verified (k1 = node_linear | zero(out)+hist, memset,
// lookback scan, scatter).

#define N_NODES 40000
#define N_EDGES 640000
#define IN_CH 128
#define OUT_CH 128
#define NUM_RBF 64

#define TILE_M 64
#define NTILES (N_EDGES / TILE_M)   // 10000
#define NB_NODE (N_NODES / 64)      // 625
#define RBF_STR 72   // ushorts
#define T_STR 136    // ushorts
#define HV_STR 136   // ushorts
#define W1_STR 72
#define W2_STR 136
#define NSCB ((N_NODES + 255) / 256)  // 157
#define EDGE_GRID 1024
#define K1_GRID 1024

typedef __attribute__((ext_vector_type(8))) short bf16x8;
typedef __attribute__((ext_vector_type(16))) float f32x16;

__device__ __forceinline__ unsigned short f2bf(float f) {
  unsigned u = __float_as_uint(f);
  return (unsigned short)((u + 0x7FFFu + ((u >> 16) & 1u)) >> 16);
}
__device__ __forceinline__ float bf2f(unsigned short s) {
  return __uint_as_float(((unsigned)s) << 16);
}

// ---------------------------------------------------------------------------
// K1: node_linear (blk<625) | zero(out)+hist (blk>=625)
// ---------------------------------------------------------------------------
__global__ __launch_bounds__(256) void k1_kernel(
    const float* __restrict__ x, const float* __restrict__ Wl,
    const float* __restrict__ bl, unsigned short* __restrict__ hbf,
    const int* __restrict__ rowI, int* __restrict__ count,
    float* __restrict__ outp) {
  __shared__ __align__(16) char pool[IN_CH * W2_STR * 2];  // 34816 B
  const int bid = blockIdx.x;
  const int t = threadIdx.x;

  if (bid >= NB_NODE) {
    const int nb = K1_GRID - NB_NODE;
    if (outp) {
      float4 z = {0.f, 0.f, 0.f, 0.f};
      for (int i = (bid - NB_NODE) * 256 + t; i < N_NODES * OUT_CH / 4;
           i += nb * 256)
        ((float4*)outp)[i] = z;
    }
    if (count) {
      for (int e = (bid - NB_NODE) * 256 + t; e < N_EDGES; e += nb * 256)
        atomicAdd(&count[rowI[e]], 1);
    }
    return;
  }

  const int lane = t & 63;
  const int l31 = lane & 31;
  const int lhalf = lane >> 5;
  const int wv = t >> 6;
  const int nbase = wv * 32 + l31;

  {
    unsigned short* sWT = (unsigned short*)pool;
    const int k2 = t >> 1;
    const int d0 = (t & 1) * 64;
#pragma unroll
    for (int i = 0; i < 16; ++i) {
      float4 v = *(const float4*)(Wl + k2 * OUT_CH + d0 + 4 * i);
      sWT[(d0 + 4 * i + 0) * W2_STR + k2] = f2bf(v.x);
      sWT[(d0 + 4 * i + 1) * W2_STR + k2] = f2bf(v.y);
      sWT[(d0 + 4 * i + 2) * W2_STR + k2] = f2bf(v.z);
      sWT[(d0 + 4 * i + 3) * W2_STR + k2] = f2bf(v.w);
    }
  }
  __syncthreads();
  bf16x8 BW[8];
  {
    const unsigned short* sWT = (const unsigned short*)pool;
#pragma unroll
    for (int kk = 0; kk < 8; ++kk)
      BW[kk] = *(const bf16x8*)&sWT[nbase * W2_STR + kk * 16 + lhalf * 8];
  }
  const float blv = bl[nbase];
  __syncthreads();

  const int rbase = bid * 64;
  unsigned short* sX = (unsigned short*)pool;
  {
    const int m = t >> 2;
    const int c0 = (t & 3) * 32;
    const float* src = x + (size_t)(rbase + m) * IN_CH + c0;
#pragma unroll
    for (int i = 0; i < 8; ++i) {
      float4 v = *(const float4*)(src + 4 * i);
      ushort4 p;
      p.x = f2bf(v.x); p.y = f2bf(v.y); p.z = f2bf(v.z); p.w = f2bf(v.w);
      *(ushort4*)&sX[m * T_STR + c0 + 4 * i] = p;
    }
  }
  __syncthreads();
#pragma unroll
  for (int mt = 0; mt < 2; ++mt) {
    f32x16 acc = {0.f, 0.f, 0.f, 0.f, 0.f, 0.f, 0.f, 0.f,
                  0.f, 0.f, 0.f, 0.f, 0.f, 0.f, 0.f, 0.f};
#pragma unroll
    for (int kk = 0; kk < 8; ++kk) {
      bf16x8 A = *(const bf16x8*)&sX[(mt * 32 + l31) * T_STR + kk * 16 + lhalf * 8];
      acc = __builtin_amdgcn_mfma_f32_32x32x16_bf16(A, BW[kk], acc, 0, 0, 0);
    }
#pragma unroll
    for (int r = 0; r < 16; ++r) {
      const int rowm = mt * 32 + (r & 3) + 8 * (r >> 2) + 4 * lhalf;
      hbf[(size_t)(rbase + rowm) * OUT_CH + nbase] = f2bf(acc[r] + blv);
    }
  }
}

// ---------------------------------------------------------------------------
// K2: single-dispatch decoupled-lookback exclusive scan -> cursor
// ---------------------------------------------------------------------------
__global__ __launch_bounds__(256) void scan_kernel(
    const int* __restrict__ count, unsigned long long* __restrict__ status,
    int* __restrict__ cursor) {
  __shared__ int s[256];
  __shared__ int wsum[4];
  const int t = threadIdx.x;
  const int b = blockIdx.x;
  const int i = b * 256 + t;
  const int v = (i < N_NODES) ? count[i] : 0;
  s[t] = v;
  __syncthreads();
  for (int off = 1; off < 256; off <<= 1) {
    int u = (t >= off) ? s[t - off] : 0;
    __syncthreads();
    s[t] += u;
    __syncthreads();
  }
  if (t == 255)
    __hip_atomic_store(&status[b], (1ULL << 32) | (unsigned)s[255],
                       __ATOMIC_RELEASE, __HIP_MEMORY_SCOPE_AGENT);
  int contrib = 0;
  if (t < b) {  // b <= 156 < 255: one predecessor per thread
    unsigned long long sv;
    do {
      sv = __hip_atomic_load(&status[t], __ATOMIC_ACQUIRE,
                             __HIP_MEMORY_SCOPE_AGENT);
    } while (!(sv >> 32));
    contrib = (int)(unsigned)sv;
  }
  for (int o = 32; o > 0; o >>= 1) contrib += __shfl_down(contrib, o, 64);
  if ((t & 63) == 0) wsum[t >> 6] = contrib;
  __syncthreads();
  const int boffv = wsum[0] + wsum[1] + wsum[2] + wsum[3];
  if (i < N_NODES) cursor[i] = boffv + s[t] - v;
}

// ---------------------------------------------------------------------------
// K3: scatter -> eperm / dsts / cols (round-1 three-array form)
// ---------------------------------------------------------------------------
__global__ void scatter_kernel(const int* __restrict__ rowI,
                               const int* __restrict__ colI,
                               int* __restrict__ cursor,
                               int* __restrict__ eperm, int* __restrict__ dsts,
                               int* __restrict__ cols) {
  int e = blockIdx.x * 256 + threadIdx.x;
  if (e < N_EDGES) {
    const int r = rowI[e];
    const int p = atomicAdd(&cursor[r], 1);
    eperm[p] = e;
    dsts[p] = r;
    cols[p] = colI[e];
  }
}

// ---------------------------------------------------------------------------
// K4: fused filter + modulate + segmented reduce, sorted order.
// Round-1 body + T14 rbf issue-early (loads for tile t+grid issued after
// barrier (c), consumed at top of next iteration; vmcnt(0) drain at the next
// __syncthreads lands after GEMM2+atomics -> HBM latency hidden).
// ---------------------------------------------------------------------------
__global__ __launch_bounds__(256, 4) void edge_fused_kernel(
    const int* __restrict__ eperm, const float* __restrict__ rbf,
    const float* __restrict__ W1, const float* __restrict__ b1,
    const float* __restrict__ W2, const float* __restrict__ b2,
    const unsigned short* __restrict__ hbf, const int* __restrict__ dsts,
    const int* __restrict__ cols, float* __restrict__ outp) {
  __shared__ __align__(16) char pool[IN_CH * W2_STR * 2];  // 34816 B

  unsigned short* sHv = (unsigned short*)pool;                            // 17408
  unsigned short* sT = (unsigned short*)pool;                             // overlap
  unsigned short* sRbf = (unsigned short*)(pool + TILE_M * HV_STR * 2);   // 9216
  int* sAux = (int*)(pool + TILE_M * HV_STR * 2 + TILE_M * RBF_STR * 2);  // 256

  const int t = threadIdx.x;
  const int lane = t & 63;
  const int l31 = lane & 31;
  const int lhalf = lane >> 5;
  const int wv = t >> 6;
  const int nbase = wv * 32 + l31;

  // ---- weight fragments (pool reused twice) ----
  {
    unsigned short* sW1T = (unsigned short*)pool;
    const int k = t >> 2;
    const int c0 = (t & 3) * 32;
#pragma unroll
    for (int i = 0; i < 8; ++i) {
      float4 v = *(const float4*)(W1 + k * OUT_CH + c0 + 4 * i);
      sW1T[(c0 + 4 * i + 0) * W1_STR + k] = f2bf(v.x);
      sW1T[(c0 + 4 * i + 1) * W1_STR + k] = f2bf(v.y);
      sW1T[(c0 + 4 * i + 2) * W1_STR + k] = f2bf(v.z);
      sW1T[(c0 + 4 * i + 3) * W1_STR + k] = f2bf(v.w);
    }
  }
  __syncthreads();
  bf16x8 B1[4];
  {
    const unsigned short* sW1T = (const unsigned short*)pool;
#pragma unroll
    for (int kk = 0; kk < 4; ++kk)
      B1[kk] = *(const bf16x8*)&sW1T[nbase * W1_STR + kk * 16 + lhalf * 8];
  }
  __syncthreads();
  {
    unsigned short* sW2T = (unsigned short*)pool;
    const int k2 = t >> 1;
    const int d0 = (t & 1) * 64;
#pragma unroll
    for (int i = 0; i < 16; ++i) {
      float4 v = *(const float4*)(W2 + k2 * OUT_CH + d0 + 4 * i);
      sW2T[(d0 + 4 * i + 0) * W2_STR + k2] = f2bf(v.x);
      sW2T[(d0 + 4 * i + 1) * W2_STR + k2] = f2bf(v.y);
      sW2T[(d0 + 4 * i + 2) * W2_STR + k2] = f2bf(v.z);
      sW2T[(d0 + 4 * i + 3) * W2_STR + k2] = f2bf(v.w);
    }
  }
  __syncthreads();
  bf16x8 B2[8];
  {
    const unsigned short* sW2T = (const unsigned short*)pool;
#pragma unroll
    for (int kk = 0; kk < 8; ++kk)
      B2[kk] = *(const bf16x8*)&sW2T[nbase * W2_STR + kk * 16 + lhalf * 8];
  }
  const float b1v = b1[nbase];
  const float b2v = b2[nbase];

  const int m4 = t >> 2;        // rbf row this thread stages
  const int kq = (t & 3) * 16;  // rbf col quarter

  // T14 issue-early registers: named float4 scalars only (no arrays).
  float4 rb0, rb1, rb2, rb3;
#define ISSUE_RBF(EB)                                                   \
  do {                                                                  \
    const int ep_ = eperm[(EB) + m4];                                   \
    const float* ps_ = rbf + (size_t)ep_ * NUM_RBF + kq;                \
    rb0 = *(const float4*)(ps_ + 0);                                    \
    rb1 = *(const float4*)(ps_ + 4);                                    \
    rb2 = *(const float4*)(ps_ + 8);                                    \
    rb3 = *(const float4*)(ps_ + 12);                                   \
  } while (0)

  ISSUE_RBF(blockIdx.x * TILE_M);  // blockIdx.x < NTILES always

  for (int tile = blockIdx.x; tile < NTILES; tile += gridDim.x) {
    const int ebase = tile * TILE_M;
    __syncthreads();  // (a) prev GEMM2's sT/sAux reads complete; rb loads drained

    // ---- stage rbf (from issued regs) + hbf rows -> sHv + dst ----
    {
      ushort4 p;
      p.x = f2bf(rb0.x); p.y = f2bf(rb0.y); p.z = f2bf(rb0.z); p.w = f2bf(rb0.w);
      *(ushort4*)&sRbf[m4 * RBF_STR + kq + 0] = p;
      p.x = f2bf(rb1.x); p.y = f2bf(rb1.y); p.z = f2bf(rb1.z); p.w = f2bf(rb1.w);
      *(ushort4*)&sRbf[m4 * RBF_STR + kq + 4] = p;
      p.x = f2bf(rb2.x); p.y = f2bf(rb2.y); p.z = f2bf(rb2.z); p.w = f2bf(rb2.w);
      *(ushort4*)&sRbf[m4 * RBF_STR + kq + 8] = p;
      p.x = f2bf(rb3.x); p.y = f2bf(rb3.y); p.z = f2bf(rb3.z); p.w = f2bf(rb3.w);
      *(ushort4*)&sRbf[m4 * RBF_STR + kq + 12] = p;
      // 64 rows x 256B of hbf, 16B per thread-chunk, 4 chunks/thread
#pragma unroll
      for (int i = 0; i < 4; ++i) {
        const int chunk = t + 256 * i;
        const int row = chunk >> 4;
        const int c8 = (chunk & 15) * 8;  // ushort offset within row
        const int col = cols[ebase + row];
        *(uint4*)&sHv[row * HV_STR + c8] =
            *(const uint4*)(hbf + (size_t)col * OUT_CH + c8);
      }
      if (t < TILE_M) sAux[t] = dsts[ebase + t];
    }
    __syncthreads();  // (b)

    // ---- h values from LDS (read BEFORE sT overwrites sHv) ----
    float hv[2][16];
#pragma unroll
    for (int mt = 0; mt < 2; ++mt)
#pragma unroll
      for (int r = 0; r < 16; ++r) {
        const int rowm = mt * 32 + (r & 3) + 8 * (r >> 2) + 4 * lhalf;
        hv[mt][r] = bf2f(sHv[rowm * HV_STR + nbase]);
      }
    __syncthreads();  // (b2) sHv reads done; sT may overwrite

    // ---- GEMM1: sT = bf16(relu(rbf @ W1 + b1)) ----
#pragma unroll
    for (int mt = 0; mt < 2; ++mt) {
      f32x16 acc = {0.f, 0.f, 0.f, 0.f, 0.f, 0.f, 0.f, 0.f,
                    0.f, 0.f, 0.f, 0.f, 0.f, 0.f, 0.f, 0.f};
#pragma unroll
      for (int kk = 0; kk < 4; ++kk) {
        bf16x8 A = *(const bf16x8*)&sRbf[(mt * 32 + l31) * RBF_STR + kk * 16 + lhalf * 8];
        acc = __builtin_amdgcn_mfma_f32_32x32x16_bf16(A, B1[kk], acc, 0, 0, 0);
      }
#pragma unroll
      for (int r = 0; r < 16; ++r) {
        const int rowm = (r & 3) + 8 * (r >> 2) + 4 * lhalf;
        float v = acc[r] + b1v;
        v = v > 0.f ? v : 0.f;
        sT[(mt * 32 + rowm) * T_STR + nbase] = f2bf(v);
      }
    }
    __syncthreads();  // (c) sT complete

    // ---- T14: issue next tile's rbf loads; latency hides under GEMM2 ----
    const int tn = tile + gridDim.x;
    if (tn < NTILES) ISSUE_RBF(tn * TILE_M);

    // ---- GEMM2 + modulate + in-register segmented reduce ----
    float sum = 0.f;
    int curd = -1;
#pragma unroll
    for (int mt = 0; mt < 2; ++mt) {
      f32x16 acc = {0.f, 0.f, 0.f, 0.f, 0.f, 0.f, 0.f, 0.f,
                    0.f, 0.f, 0.f, 0.f, 0.f, 0.f, 0.f, 0.f};
#pragma unroll
      for (int kk = 0; kk < 8; ++kk) {
        bf16x8 A = *(const bf16x8*)&sT[(mt * 32 + l31) * T_STR + kk * 16 + lhalf * 8];
        acc = __builtin_amdgcn_mfma_f32_32x32x16_bf16(A, B2[kk], acc, 0, 0, 0);
      }
#pragma unroll
      for (int r = 0; r < 16; ++r) {
        const int rowm = mt * 32 + (r & 3) + 8 * (r >> 2) + 4 * lhalf;
        const float m = hv[mt][r] * (acc[r] + b2v);
        const int d = sAux[rowm];
        if (d != curd) {
          if (curd >= 0) atomicAdd(&outp[(size_t)curd * OUT_CH + nbase], sum);
          curd = d;
          sum = m;
        } else {
          sum += m;
        }
      }
    }
    atomicAdd(&outp[(size_t)curd * OUT_CH + nbase], sum);
  }
#undef ISSUE_RBF
}

// ---------------------------------------------------------------------------
// Fallback: natural-order edge kernel (ws too small), sync staging
// ---------------------------------------------------------------------------
__global__ __launch_bounds__(256, 4) void edge_atomic_kernel(
    const int* __restrict__ eidx, const float* __restrict__ rbf,
    const float* __restrict__ W1, const float* __restrict__ b1,
    const float* __restrict__ W2, const float* __restrict__ b2,
    const unsigned short* __restrict__ hbf, float* __restrict__ outp) {
  __shared__ __align__(16) char pool[IN_CH * W2_STR * 2];

  unsigned short* sHv = (unsigned short*)pool;
  unsigned short* sT = (unsigned short*)pool;
  unsigned short* sRbf = (unsigned short*)(pool + TILE_M * HV_STR * 2);
  int* sAux = (int*)(pool + TILE_M * HV_STR * 2 + TILE_M * RBF_STR * 2);

  const int t = threadIdx.x;
  const int lane = t & 63;
  const int l31 = lane & 31;
  const int lhalf = lane >> 5;
  const int wv = t >> 6;
  const int nbase = wv * 32 + l31;

  {
    unsigned short* sW1T = (unsigned short*)pool;
    const int k = t >> 2;
    const int c0 = (t & 3) * 32;
#pragma unroll
    for (int i = 0; i < 8; ++i) {
      float4 v = *(const float4*)(W1 + k * OUT_CH + c0 + 4 * i);
      sW1T[(c0 + 4 * i + 0) * W1_STR + k] = f2bf(v.x);
      sW1T[(c0 + 4 * i + 1) * W1_STR + k] = f2bf(v.y);
      sW1T[(c0 + 4 * i + 2) * W1_STR + k] = f2bf(v.z);
      sW1T[(c0 + 4 * i + 3) * W1_STR + k] = f2bf(v.w);
    }
  }
  __syncthreads();
  bf16x8 B1[4];
  {
    const unsigned short* sW1T = (const unsigned short*)pool;
#pragma unroll
    for (int kk = 0; kk < 4; ++kk)
      B1[kk] = *(const bf16x8*)&sW1T[nbase * W1_STR + kk * 16 + lhalf * 8];
  }
  __syncthreads();
  {
    unsigned short* sW2T = (unsigned short*)pool;
    const int k2 = t >> 1;
    const int d0 = (t & 1) * 64;
#pragma unroll
    for (int i = 0; i < 16; ++i) {
      float4 v = *(const float4*)(W2 + k2 * OUT_CH + d0 + 4 * i);
      sW2T[(d0 + 4 * i + 0) * W2_STR + k2] = f2bf(v.x);
      sW2T[(d0 + 4 * i + 1) * W2_STR + k2] = f2bf(v.y);
      sW2T[(d0 + 4 * i + 2) * W2_STR + k2] = f2bf(v.z);
      sW2T[(d0 + 4 * i + 3) * W2_STR + k2] = f2bf(v.w);
    }
  }
  __syncthreads();
  bf16x8 B2[8];
  {
    const unsigned short* sW2T = (const unsigned short*)pool;
#pragma unroll
    for (int kk = 0; kk < 8; ++kk)
      B2[kk] = *(const bf16x8*)&sW2T[nbase * W2_STR + kk * 16 + lhalf * 8];
  }
  const float b1v = b1[nbase];
  const float b2v = b2[nbase];

  const int* rowI = eidx;
  const int* colI = eidx + N_EDGES;

  for (int tile = blockIdx.x; tile < NTILES; tile += gridDim.x) {
    const int ebase = tile * TILE_M;
    __syncthreads();
    {
      const int m = t >> 2;
      const int kq = (t & 3) * 16;
      const float* src = rbf + (size_t)(ebase + m) * NUM_RBF + kq;
#pragma unroll
      for (int i = 0; i < 4; ++i) {
        float4 v = *(const float4*)(src + 4 * i);
        ushort4 p;
        p.x = f2bf(v.x); p.y = f2bf(v.y); p.z = f2bf(v.z); p.w = f2bf(v.w);
        *(ushort4*)&sRbf[m * RBF_STR + kq + 4 * i] = p;
      }
#pragma unroll
      for (int i = 0; i < 4; ++i) {
        const int chunk = t + 256 * i;
        const int row = chunk >> 4;
        const int c8 = (chunk & 15) * 8;
        const int col = colI[ebase + row];
        *(uint4*)&sHv[row * HV_STR + c8] =
            *(const uint4*)(hbf + (size_t)col * OUT_CH + c8);
      }
      if (t < TILE_M) sAux[t] = rowI[ebase + t];
    }
    __syncthreads();

    float hv[2][16];
#pragma unroll
    for (int mt = 0; mt < 2; ++mt)
#pragma unroll
      for (int r = 0; r < 16; ++r) {
        const int rowm = mt * 32 + (r & 3) + 8 * (r >> 2) + 4 * lhalf;
        hv[mt][r] = bf2f(sHv[rowm * HV_STR + nbase]);
      }
    __syncthreads();

#pragma unroll
    for (int mt = 0; mt < 2; ++mt) {
      f32x16 acc = {0.f, 0.f, 0.f, 0.f, 0.f, 0.f, 0.f, 0.f,
                    0.f, 0.f, 0.f, 0.f, 0.f, 0.f, 0.f, 0.f};
#pragma unroll
      for (int kk = 0; kk < 4; ++kk) {
        bf16x8 A = *(const bf16x8*)&sRbf[(mt * 32 + l31) * RBF_STR + kk * 16 + lhalf * 8];
        acc = __builtin_amdgcn_mfma_f32_32x32x16_bf16(A, B1[kk], acc, 0, 0, 0);
      }
#pragma unroll
      for (int r = 0; r < 16; ++r) {
        const int rowm = (r & 3) + 8 * (r >> 2) + 4 * lhalf;
        float v = acc[r] + b1v;
        v = v > 0.f ? v : 0.f;
        sT[(mt * 32 + rowm) * T_STR + nbase] = f2bf(v);
      }
    }
    __syncthreads();

    float sum = 0.f;
    int curd = -1;
#pragma unroll
    for (int mt = 0; mt < 2; ++mt) {
      f32x16 acc = {0.f, 0.f, 0.f, 0.f, 0.f, 0.f, 0.f, 0.f,
                    0.f, 0.f, 0.f, 0.f, 0.f, 0.f, 0.f, 0.f};
#pragma unroll
      for (int kk = 0; kk < 8; ++kk) {
        bf16x8 A = *(const bf16x8*)&sT[(mt * 32 + l31) * T_STR + kk * 16 + lhalf * 8];
        acc = __builtin_amdgcn_mfma_f32_32x32x16_bf16(A, B2[kk], acc, 0, 0, 0);
      }
#pragma unroll
      for (int r = 0; r < 16; ++r) {
        const int rowm = mt * 32 + (r & 3) + 8 * (r >> 2) + 4 * lhalf;
        const float m = hv[mt][r] * (acc[r] + b2v);
        const int d = sAux[rowm];
        if (d != curd) {
          if (curd >= 0) atomicAdd(&outp[(size_t)curd * OUT_CH + nbase], sum);
          curd = d;
          sum = m;
        } else {
          sum += m;
        }
      }
    }
    atomicAdd(&outp[(size_t)curd * OUT_CH + nbase], sum);
  }
}

// ---------------------------------------------------------------------------
extern "C" void kernel_launch(void* const* d_in, const int* in_sizes, int n_in,
                              void* d_out, int out_size, void* d_ws, size_t ws_size,
                              hipStream_t stream) {
  const float* x    = (const float*)d_in[0];
  const int*   eidx = (const int*)d_in[1];
  const float* rbf  = (const float*)d_in[2];
  const float* W1   = (const float*)d_in[3];
  const float* b1   = (const float*)d_in[4];
  const float* W2   = (const float*)d_in[5];
  const float* b2   = (const float*)d_in[6];
  const float* Wl   = (const float*)d_in[7];
  const float* bl   = (const float*)d_in[8];
  float* out = (float*)d_out;

  char* ws = (char*)d_ws;
  const size_t HBF_B = (size_t)N_NODES * OUT_CH * 2;   // 10,240,000
  const size_t EP_B = (size_t)N_EDGES * 4;             //  2,560,000 (x3)
  const size_t CNT_B = (size_t)N_NODES * 4;            //    160,000 (x2)
  const size_t ST_B = 1280;
  const size_t need = HBF_B + 3 * EP_B + 2 * CNT_B + ST_B + 64;

  size_t off = 0;
  unsigned short* hbf = (unsigned short*)(ws + off); off += HBF_B;
  int* eperm = (int*)(ws + off); off += EP_B;
  int* dsts  = (int*)(ws + off); off += EP_B;
  int* cols  = (int*)(ws + off); off += EP_B;
  int* count = (int*)(ws + off); off += CNT_B;
  unsigned long long* status = (unsigned long long*)(ws + off); off += ST_B;
  int* cursor = (int*)(ws + off); off += CNT_B;

  const int* rowI = eidx;
  const int* colI = eidx + N_EDGES;

  if (ws_size >= need) {
    hipMemsetAsync(count, 0, CNT_B + ST_B, stream);  // count + status
    k1_kernel<<<K1_GRID, 256, 0, stream>>>(x, Wl, bl, hbf, rowI, count, out);
    scan_kernel<<<NSCB, 256, 0, stream>>>(count, status, cursor);
    scatter_kernel<<<(N_EDGES + 255) / 256, 256, 0, stream>>>(
        rowI, colI, cursor, eperm, dsts, cols);
    edge_fused_kernel<<<EDGE_GRID, 256, 0, stream>>>(
        eperm, rbf, W1, b1, W2, b2, hbf, dsts, cols, out);
  } else {
    hipMemsetAsync(out, 0, (size_t)N_NODES * OUT_CH * sizeof(float), stream);
    k1_kernel<<<NB_NODE, 256, 0, stream>>>(x, Wl, bl, hbf, rowI, nullptr,
                                           nullptr);
    edge_atomic_kernel<<<EDGE_GRID, 256, 0, stream>>>(
        eidx, rbf, W1, b1, W2, b2, hbf, out);
  }
}